// Round 1
// baseline (8995.322 us; speedup 1.0000x reference)
//
#include <hip/hip_runtime.h>
#include <hip/hip_bf16.h>

// MSAAttentionBlock: fused per-voxel pipeline.
// Round 1: fp32 VALU baseline, correctness + structure. TILE=16 voxels/block.
// Stages: load x -> QKV -> per-(voxel,head) attention -> FFN1(relu) -> FFN2
//         -> residual conv (relu) -> batchnorm -> out.

#define TILE 16
#define THREADS 256

constexpr int CIN = 256;   // input channels
constexpr int NQK = 512;   // NH*DK
constexpr int NV  = 256;   // NH*DV
constexpr int NI  = 1024;  // 2*NH*DK

// LDS layout (float offsets). Dynamic shared, 28928 floats = 113 KB.
constexpr int OFF_XS = 0;            // [16][256]  x tile (persists for residual)
constexpr int OFF_QS = 4096;         // [16][516]  q (padded row)
constexpr int OFF_KS = 12352;        // [16][516]  k
constexpr int OFF_VS = 20608;        // [16][260]  v
constexpr int OFF_AO = 24768;        // [16][260]  attention output
constexpr int OFF_IN = 4096;         // [16][1024] FFN intermediate (aliases q,k — dead then)
constexpr int SMEM_FLOATS = 28928;

__global__ __launch_bounds__(THREADS, 1)
void msa_fused(const float* __restrict__ x,
               const float* __restrict__ Wq, const float* __restrict__ bq,
               const float* __restrict__ Wk, const float* __restrict__ bk,
               const float* __restrict__ Wv, const float* __restrict__ bv,
               const float* __restrict__ W1, const float* __restrict__ b1,
               const float* __restrict__ Wo, const float* __restrict__ bo,
               const float* __restrict__ Wc, const float* __restrict__ bc,
               const float* __restrict__ gamma, const float* __restrict__ beta,
               const float* __restrict__ mu, const float* __restrict__ var,
               float* __restrict__ out)
{
    extern __shared__ float sm[];
    const int t = threadIdx.x;
    const int base = blockIdx.x * (TILE * CIN);

    // ---- load x tile (coalesced: one row per iteration) ----
    #pragma unroll
    for (int r = 0; r < TILE; ++r)
        sm[OFF_XS + r * CIN + t] = x[base + r * CIN + t];
    __syncthreads();

    // ---- QKV projections: thread t owns cols {t, t+256} of q,k and col t of v ----
    {
        float aq0[TILE], aq1[TILE], ak0[TILE], ak1[TILE], av0[TILE];
        #pragma unroll
        for (int r = 0; r < TILE; ++r) { aq0[r]=0.f; aq1[r]=0.f; ak0[r]=0.f; ak1[r]=0.f; av0[r]=0.f; }
        const int c0 = t, c1 = t + 256;
        for (int kk = 0; kk < CIN; kk += 4) {
            float4 xr[TILE];
            #pragma unroll
            for (int r = 0; r < TILE; ++r)
                xr[r] = *(const float4*)&sm[OFF_XS + r * CIN + kk];  // uniform broadcast
            #pragma unroll
            for (int u = 0; u < 4; ++u) {
                const int kc = kk + u;
                const float wq0 = Wq[kc * NQK + c0];
                const float wq1 = Wq[kc * NQK + c1];
                const float wk0 = Wk[kc * NQK + c0];
                const float wk1 = Wk[kc * NQK + c1];
                const float wv  = Wv[kc * NV  + c0];
                #pragma unroll
                for (int r = 0; r < TILE; ++r) {
                    const float xv = ((const float*)&xr[r])[u];
                    aq0[r] = fmaf(xv, wq0, aq0[r]);
                    aq1[r] = fmaf(xv, wq1, aq1[r]);
                    ak0[r] = fmaf(xv, wk0, ak0[r]);
                    ak1[r] = fmaf(xv, wk1, ak1[r]);
                    av0[r] = fmaf(xv, wv , av0[r]);
                }
            }
        }
        const float bq0 = bq[c0], bq1 = bq[c1];
        const float bk0 = bk[c0], bk1 = bk[c1];
        const float bv0 = bv[c0];
        #pragma unroll
        for (int r = 0; r < TILE; ++r) {
            sm[OFF_QS + r * 516 + c0] = aq0[r] + bq0;
            sm[OFF_QS + r * 516 + c1] = aq1[r] + bq1;
            sm[OFF_KS + r * 516 + c0] = ak0[r] + bk0;
            sm[OFF_KS + r * 516 + c1] = ak1[r] + bk1;
            sm[OFF_VS + r * 260 + c0] = av0[r] + bv0;
        }
    }
    __syncthreads();

    // ---- attention: one thread per (voxel vx, head h); softmax over 16 in regs ----
    {
        const int vx = t >> 4;
        const int h  = t & 15;
        float qreg[32];
        #pragma unroll
        for (int d = 0; d < 32; d += 4) {
            const float4 f = *(const float4*)&sm[OFF_QS + vx * 516 + h * 32 + d];
            qreg[d+0] = f.x; qreg[d+1] = f.y; qreg[d+2] = f.z; qreg[d+3] = f.w;
        }
        float sc[16];
        #pragma unroll
        for (int g = 0; g < 16; ++g) {
            float s = 0.f;
            #pragma unroll
            for (int d = 0; d < 32; d += 4) {
                const float4 kf = *(const float4*)&sm[OFF_KS + vx * 516 + g * 32 + d];
                s = fmaf(qreg[d+0], kf.x, s);
                s = fmaf(qreg[d+1], kf.y, s);
                s = fmaf(qreg[d+2], kf.z, s);
                s = fmaf(qreg[d+3], kf.w, s);
            }
            sc[g] = s * 0.17677669529663687f;  // 1/sqrt(32)
        }
        float m = sc[0];
        #pragma unroll
        for (int g = 1; g < 16; ++g) m = fmaxf(m, sc[g]);
        float sum = 0.f;
        #pragma unroll
        for (int g = 0; g < 16; ++g) { sc[g] = __expf(sc[g] - m); sum += sc[g]; }
        const float inv = 1.f / sum;
        float ao[16];
        #pragma unroll
        for (int vv = 0; vv < 16; ++vv) ao[vv] = 0.f;
        #pragma unroll
        for (int g = 0; g < 16; ++g) {
            const float a = sc[g];
            #pragma unroll
            for (int vv = 0; vv < 16; vv += 4) {
                const float4 vf = *(const float4*)&sm[OFF_VS + vx * 260 + g * 16 + vv];
                ao[vv+0] = fmaf(a, vf.x, ao[vv+0]);
                ao[vv+1] = fmaf(a, vf.y, ao[vv+1]);
                ao[vv+2] = fmaf(a, vf.z, ao[vv+2]);
                ao[vv+3] = fmaf(a, vf.w, ao[vv+3]);
            }
        }
        #pragma unroll
        for (int vv = 0; vv < 16; vv += 4) {
            float4 o;
            o.x = ao[vv+0] * inv; o.y = ao[vv+1] * inv;
            o.z = ao[vv+2] * inv; o.w = ao[vv+3] * inv;
            *(float4*)&sm[OFF_AO + vx * 260 + h * 16 + vv] = o;
        }
    }
    __syncthreads();

    // ---- FFN1: inter = relu(ao @ W1 + b1), thread owns cols {t, t+256, t+512, t+768} ----
    {
        float a1_0[TILE], a1_1[TILE], a1_2[TILE], a1_3[TILE];
        #pragma unroll
        for (int r = 0; r < TILE; ++r) { a1_0[r]=0.f; a1_1[r]=0.f; a1_2[r]=0.f; a1_3[r]=0.f; }
        for (int kk = 0; kk < NV; kk += 4) {
            float4 ar[TILE];
            #pragma unroll
            for (int r = 0; r < TILE; ++r)
                ar[r] = *(const float4*)&sm[OFF_AO + r * 260 + kk];
            #pragma unroll
            for (int u = 0; u < 4; ++u) {
                const int kc = kk + u;
                const float w0 = W1[kc * NI + t      ];
                const float w1 = W1[kc * NI + t + 256];
                const float w2 = W1[kc * NI + t + 512];
                const float w3 = W1[kc * NI + t + 768];
                #pragma unroll
                for (int r = 0; r < TILE; ++r) {
                    const float xv = ((const float*)&ar[r])[u];
                    a1_0[r] = fmaf(xv, w0, a1_0[r]);
                    a1_1[r] = fmaf(xv, w1, a1_1[r]);
                    a1_2[r] = fmaf(xv, w2, a1_2[r]);
                    a1_3[r] = fmaf(xv, w3, a1_3[r]);
                }
            }
        }
        const float b10 = b1[t], b11 = b1[t+256], b12 = b1[t+512], b13 = b1[t+768];
        #pragma unroll
        for (int r = 0; r < TILE; ++r) {
            sm[OFF_IN + r * NI + t      ] = fmaxf(a1_0[r] + b10, 0.f);
            sm[OFF_IN + r * NI + t + 256] = fmaxf(a1_1[r] + b11, 0.f);
            sm[OFF_IN + r * NI + t + 512] = fmaxf(a1_2[r] + b12, 0.f);
            sm[OFF_IN + r * NI + t + 768] = fmaxf(a1_3[r] + b13, 0.f);
        }
    }
    __syncthreads();

    // ---- FFN2 + residual conv + batchnorm: thread owns output channel t ----
    {
        float a2[TILE];
        #pragma unroll
        for (int r = 0; r < TILE; ++r) a2[r] = 0.f;
        for (int kk = 0; kk < NI; kk += 4) {
            float4 ir[TILE];
            #pragma unroll
            for (int r = 0; r < TILE; ++r)
                ir[r] = *(const float4*)&sm[OFF_IN + r * NI + kk];
            #pragma unroll
            for (int u = 0; u < 4; ++u) {
                const float wo_ = Wo[(kk + u) * NV + t];
                #pragma unroll
                for (int r = 0; r < TILE; ++r)
                    a2[r] = fmaf(((const float*)&ir[r])[u], wo_, a2[r]);
            }
        }
        float ar_[TILE];
        #pragma unroll
        for (int r = 0; r < TILE; ++r) ar_[r] = 0.f;
        for (int kk = 0; kk < CIN; kk += 4) {
            float4 xr[TILE];
            #pragma unroll
            for (int r = 0; r < TILE; ++r)
                xr[r] = *(const float4*)&sm[OFF_XS + r * CIN + kk];
            #pragma unroll
            for (int u = 0; u < 4; ++u) {
                const float wc_ = Wc[(kk + u) * NV + t];
                #pragma unroll
                for (int r = 0; r < TILE; ++r)
                    ar_[r] = fmaf(((const float*)&xr[r])[u], wc_, ar_[r]);
            }
        }
        const float bo_ = bo[t], bc_ = bc[t];
        const float scale = gamma[t] * rsqrtf(var[t] + 1e-6f);
        const float mu_ = mu[t], be_ = beta[t];
        #pragma unroll
        for (int r = 0; r < TILE; ++r) {
            const float resv = fmaxf(ar_[r] + bc_, 0.f);
            const float iv   = a2[r] + bo_;
            out[base + r * CIN + t] = (resv + iv - mu_) * scale + be_;
        }
    }
}

extern "C" void kernel_launch(void* const* d_in, const int* in_sizes, int n_in,
                              void* d_out, int out_size, void* d_ws, size_t ws_size,
                              hipStream_t stream) {
    const float* x     = (const float*)d_in[0];
    const float* Wq    = (const float*)d_in[1];
    const float* bq    = (const float*)d_in[2];
    const float* Wk    = (const float*)d_in[3];
    const float* bk    = (const float*)d_in[4];
    const float* Wv    = (const float*)d_in[5];
    const float* bv    = (const float*)d_in[6];
    const float* W1    = (const float*)d_in[7];
    const float* b1    = (const float*)d_in[8];
    const float* Wo    = (const float*)d_in[9];
    const float* bo    = (const float*)d_in[10];
    const float* Wc    = (const float*)d_in[11];
    const float* bc    = (const float*)d_in[12];
    const float* gamma = (const float*)d_in[13];
    const float* beta  = (const float*)d_in[14];
    const float* mu    = (const float*)d_in[15];
    const float* var   = (const float*)d_in[16];
    float* out = (float*)d_out;

    const int n = in_sizes[0] / CIN;       // 131072 voxels
    const int blocks = n / TILE;           // 8192
    const size_t smem = SMEM_FLOATS * sizeof(float);  // 113 KB dynamic LDS
    hipFuncSetAttribute(reinterpret_cast<const void*>(msa_fused),
                        hipFuncAttributeMaxDynamicSharedMemorySize, (int)smem);
    msa_fused<<<blocks, THREADS, smem, stream>>>(x, Wq, bq, Wk, bk, Wv, bv,
                                                 W1, b1, Wo, bo, Wc, bc,
                                                 gamma, beta, mu, var, out);
}

// Round 2
// 664.923 us; speedup vs baseline: 13.5284x; 13.5284x over previous
//
#include <hip/hip_runtime.h>
#include <hip/hip_bf16.h>

// MSAAttentionBlock round 2: bf16 MFMA for all GEMM stages.
// TILE=32 voxels/block, 512 threads (8 waves). Weights pre-packed to
// B-fragment order (bf16) in d_ws by pack_w. Activations in LDS in
// A-fragment order. Attention on fp32 VALU with broadcast-friendly layout.

typedef __bf16 bf16;
typedef __bf16 bf16x8 __attribute__((ext_vector_type(8)));
typedef float f32x4 __attribute__((ext_vector_type(4)));

#define MFMA(a, b, c) __builtin_amdgcn_mfma_f32_16x16x32_bf16((a), (b), (c), 0, 0, 0)

#define THREADS 512
#define TILE 32

constexpr int CIN = 256, NQK = 512, NV = 256, NI = 1024;

// packed-weight regions, in 8-element chunks (chunk = 16 B)
// layout per matrix: chunk lc = (nt*KT + kt)*64 + lane ; elems at lc*8
//   element j of chunk: B[k = kt*32 + (lane>>4)*8 + j][n = nt*16 + (lane&15)]
constexpr int CH_WQ = 0;                // 256x512  -> 16384 chunks, KT=8
constexpr int CH_WK = 16384;            // 256x512
constexpr int CH_WV = 32768;            // 256x256  -> 8192
constexpr int CH_W1 = 40960;            // 256x1024 -> 32768
constexpr int CH_WO = 73728;            // 1024x256 -> 32768, KT=32
constexpr int CH_WC = 106496;           // 256x256  -> 8192
constexpr int CH_TOT = 114688;          // * 16 B = 1.75 MB

// LDS layout (bf16 element offsets)
constexpr int L_XF  = 0;                // x A-frags:  2*8*64*8 = 8192
constexpr int L_AOF = 8192;             // ao A-frags: 8192
constexpr int L_C   = 16384;            // overlay region
constexpr int L_QS  = L_C;              // q plain [32][528]
constexpr int L_KS  = L_C + 16896;      // k plain [32][528]
constexpr int L_VS  = L_C + 33792;      // v plain [32][272]
constexpr int L_INTF = L_C;             // inter A-frags 2*32*64*8 = 32768 (aliases q/k/v)
constexpr int LDS_ELEMS = 16384 + 42496;   // 58880 bf16 = 117760 B

__global__ void pack_w(const float* __restrict__ Wq, const float* __restrict__ Wk,
                       const float* __restrict__ Wv, const float* __restrict__ W1,
                       const float* __restrict__ Wo, const float* __restrict__ Wc,
                       bf16* __restrict__ ws) {
    int c = blockIdx.x * 256 + threadIdx.x;
    if (c >= CH_TOT) return;
    const float* W; int N, KT, lc;
    if (c < CH_WK)      { W = Wq; N = 512;  KT = 8;  lc = c - CH_WQ; }
    else if (c < CH_WV) { W = Wk; N = 512;  KT = 8;  lc = c - CH_WK; }
    else if (c < CH_W1) { W = Wv; N = 256;  KT = 8;  lc = c - CH_WV; }
    else if (c < CH_WO) { W = W1; N = 1024; KT = 8;  lc = c - CH_W1; }
    else if (c < CH_WC) { W = Wo; N = 256;  KT = 32; lc = c - CH_WO; }
    else                { W = Wc; N = 256;  KT = 8;  lc = c - CH_WC; }
    int lane = lc & 63, tmp = lc >> 6;
    int kt = tmp % KT, nt = tmp / KT;
    int k0 = kt * 32 + (lane >> 4) * 8;
    int n  = nt * 16 + (lane & 15);
    bf16x8 v;
    #pragma unroll
    for (int j = 0; j < 8; ++j) v[j] = (bf16)W[(size_t)(k0 + j) * N + n];
    *(bf16x8*)(ws + (size_t)c * 8) = v;
}

__device__ __forceinline__ bf16x8 lds_afrag(const bf16* smb, int baseoff, int KT,
                                            int mt, int kt, int lane) {
    return *(const bf16x8*)(smb + baseoff + (((mt * KT + kt) * 64) + lane) * 8);
}

__global__ __launch_bounds__(THREADS)
void msa_mfma(const float* __restrict__ x, const bf16* __restrict__ ws,
              const float* __restrict__ bq, const float* __restrict__ bk,
              const float* __restrict__ bv, const float* __restrict__ b1,
              const float* __restrict__ bo, const float* __restrict__ bc,
              const float* __restrict__ gamma, const float* __restrict__ beta,
              const float* __restrict__ mu, const float* __restrict__ var,
              float* __restrict__ out)
{
    extern __shared__ bf16 smb[];
    const int t = threadIdx.x;
    const int lane = t & 63;
    const int wave = t >> 6;
    const int col = lane & 15;
    const int qd  = lane >> 4;
    const size_t base = (size_t)blockIdx.x * (TILE * CIN);

    // ---- stage 0: load x, convert to bf16, store in A-frag order ----
    #pragma unroll
    for (int c2 = t; c2 < 1024; c2 += THREADS) {
        int lc = c2 & 63, kt = (c2 >> 6) & 7, mt = c2 >> 9;
        int vox = mt * 16 + (lc & 15);
        int k0  = kt * 32 + (lc >> 4) * 8;
        const float* src = x + base + vox * 256 + k0;
        float4 f0 = *(const float4*)src;
        float4 f1 = *(const float4*)(src + 4);
        bf16x8 h;
        h[0] = (bf16)f0.x; h[1] = (bf16)f0.y; h[2] = (bf16)f0.z; h[3] = (bf16)f0.w;
        h[4] = (bf16)f1.x; h[5] = (bf16)f1.y; h[6] = (bf16)f1.z; h[7] = (bf16)f1.w;
        *(bf16x8*)&smb[L_XF + c2 * 8] = h;
    }
    __syncthreads();

    // ---- stage 1: QKV GEMM. 80 n-tiles (q:0-31, k:32-63, v:64-79), 10/wave ----
    {
        f32x4 acc[10][2];
        #pragma unroll
        for (int i = 0; i < 10; ++i) {
            acc[i][0] = (f32x4){0.f, 0.f, 0.f, 0.f};
            acc[i][1] = (f32x4){0.f, 0.f, 0.f, 0.f};
        }
        const bf16* wbase[10];
        #pragma unroll
        for (int i = 0; i < 10; ++i) {
            int g = wave * 10 + i;
            int ch;
            if (g < 32)      ch = CH_WQ + g * 512;          // nt*KT*64 = g*8*64
            else if (g < 64) ch = CH_WK + (g - 32) * 512;
            else             ch = CH_WV + (g - 64) * 512;
            wbase[i] = ws + ((size_t)ch + lane) * 8;
        }
        for (int kt = 0; kt < 8; ++kt) {
            bf16x8 a0 = lds_afrag(smb, L_XF, 8, 0, kt, lane);
            bf16x8 a1 = lds_afrag(smb, L_XF, 8, 1, kt, lane);
            #pragma unroll
            for (int i = 0; i < 10; ++i) {
                bf16x8 b = *(const bf16x8*)(wbase[i] + kt * 512);
                acc[i][0] = MFMA(a0, b, acc[i][0]);
                acc[i][1] = MFMA(a1, b, acc[i][1]);
            }
        }
        // epilogue: +bias, cvt bf16, scatter to plain q/k/v
        #pragma unroll
        for (int i = 0; i < 10; ++i) {
            int g = wave * 10 + i;
            int plane, stride, chan;
            float bias;
            if (g < 32)      { chan = g * 16 + col;        bias = bq[chan]; plane = L_QS; stride = 528; }
            else if (g < 64) { chan = (g - 32) * 16 + col; bias = bk[chan]; plane = L_KS; stride = 528; }
            else             { chan = (g - 64) * 16 + col; bias = bv[chan]; plane = L_VS; stride = 272; }
            #pragma unroll
            for (int mt = 0; mt < 2; ++mt)
                #pragma unroll
                for (int r = 0; r < 4; ++r) {
                    int vox = mt * 16 + qd * 4 + r;
                    smb[plane + vox * stride + chan] = (bf16)(acc[i][mt][r] + bias);
                }
        }
    }
    __syncthreads();

    // ---- stage 2: attention, one thread per (voxel, head), fp32 VALU ----
    {
        const int vox = t >> 4, h = t & 15;
        const bf16* qp = smb + L_QS + vox * 528 + h * 32;
        float qf[32];
        #pragma unroll
        for (int d8 = 0; d8 < 4; ++d8) {
            bf16x8 qv = *(const bf16x8*)(qp + d8 * 8);
            #pragma unroll
            for (int j = 0; j < 8; ++j) qf[d8 * 8 + j] = (float)qv[j];
        }
        float sc_[16];
        #pragma unroll
        for (int g = 0; g < 16; ++g) {
            const bf16* kp = smb + L_KS + vox * 528 + g * 32;  // broadcast across h
            float s = 0.f;
            #pragma unroll
            for (int d8 = 0; d8 < 4; ++d8) {
                bf16x8 kv = *(const bf16x8*)(kp + d8 * 8);
                #pragma unroll
                for (int j = 0; j < 8; ++j) s = fmaf((float)kv[j], qf[d8 * 8 + j], s);
            }
            sc_[g] = s * 0.17677669529663687f;   // 1/sqrt(32)
        }
        float m = sc_[0];
        #pragma unroll
        for (int g = 1; g < 16; ++g) m = fmaxf(m, sc_[g]);
        float sum = 0.f;
        #pragma unroll
        for (int g = 0; g < 16; ++g) { sc_[g] = __expf(sc_[g] - m); sum += sc_[g]; }
        const float inv = 1.f / sum;
        float ao[16];
        #pragma unroll
        for (int j = 0; j < 16; ++j) ao[j] = 0.f;
        #pragma unroll
        for (int g = 0; g < 16; ++g) {
            const float a = sc_[g];
            const bf16* vp = smb + L_VS + vox * 272 + g * 16;  // broadcast across h
            #pragma unroll
            for (int v8 = 0; v8 < 2; ++v8) {
                bf16x8 vv = *(const bf16x8*)(vp + v8 * 8);
                #pragma unroll
                for (int j = 0; j < 8; ++j)
                    ao[v8 * 8 + j] = fmaf(a, (float)vv[j], ao[v8 * 8 + j]);
            }
        }
        // write attn_out in A-frag order for FFN1: chan c = h*16 + half*8 + j
        const int mt = vox >> 4, m_ = vox & 15, kt = h >> 1;
        #pragma unroll
        for (int half = 0; half < 2; ++half) {
            int quad = (h & 1) * 2 + half;
            bf16x8 o;
            #pragma unroll
            for (int j = 0; j < 8; ++j) o[j] = (bf16)(ao[half * 8 + j] * inv);
            *(bf16x8*)&smb[L_AOF + (((mt * 8 + kt) * 64) + quad * 16 + m_) * 8] = o;
        }
    }
    __syncthreads();

    // ---- stage 3: FFN1 = relu(ao @ W1 + b1) -> inter A-frags ----
    {
        f32x4 acc[8][2];
        #pragma unroll
        for (int i = 0; i < 8; ++i) {
            acc[i][0] = (f32x4){0.f, 0.f, 0.f, 0.f};
            acc[i][1] = (f32x4){0.f, 0.f, 0.f, 0.f};
        }
        const int n0 = wave * 8;
        for (int kt = 0; kt < 8; ++kt) {
            bf16x8 a0 = lds_afrag(smb, L_AOF, 8, 0, kt, lane);
            bf16x8 a1 = lds_afrag(smb, L_AOF, 8, 1, kt, lane);
            #pragma unroll
            for (int i = 0; i < 8; ++i) {
                bf16x8 b = *(const bf16x8*)(ws + ((size_t)(CH_W1 + ((n0 + i) * 8 + kt) * 64) + lane) * 8);
                acc[i][0] = MFMA(a0, b, acc[i][0]);
                acc[i][1] = MFMA(a1, b, acc[i][1]);
            }
        }
        __syncthreads();   // q/k/v reads done; L_INTF aliases them
        #pragma unroll
        for (int i = 0; i < 8; ++i) {
            int c = (n0 + i) * 16 + col;
            float bias = b1[c];
            int kt2 = c >> 5;
            int q2  = (c & 31) >> 3;
            int j2  = c & 7;
            #pragma unroll
            for (int mt = 0; mt < 2; ++mt)
                #pragma unroll
                for (int r = 0; r < 4; ++r) {
                    int m_ = qd * 4 + r;
                    float v = fmaxf(acc[i][mt][r] + bias, 0.f);
                    smb[L_INTF + (((mt * 32 + kt2) * 64) + q2 * 16 + m_) * 8 + j2] = (bf16)v;
                }
        }
    }
    __syncthreads();

    // ---- stage 4: FFN2 (inter @ Wo) + residual (x @ Wc) + batchnorm ----
    {
        f32x4 accF[2][2], accW[2][2];
        #pragma unroll
        for (int i = 0; i < 2; ++i)
            #pragma unroll
            for (int mt = 0; mt < 2; ++mt) {
                accF[i][mt] = (f32x4){0.f, 0.f, 0.f, 0.f};
                accW[i][mt] = (f32x4){0.f, 0.f, 0.f, 0.f};
            }
        const int n0 = wave * 2;
        for (int kt = 0; kt < 32; ++kt) {
            bf16x8 a0 = lds_afrag(smb, L_INTF, 32, 0, kt, lane);
            bf16x8 a1 = lds_afrag(smb, L_INTF, 32, 1, kt, lane);
            #pragma unroll
            for (int i = 0; i < 2; ++i) {
                bf16x8 b = *(const bf16x8*)(ws + ((size_t)(CH_WO + ((n0 + i) * 32 + kt) * 64) + lane) * 8);
                accF[i][0] = MFMA(a0, b, accF[i][0]);
                accF[i][1] = MFMA(a1, b, accF[i][1]);
            }
        }
        for (int kt = 0; kt < 8; ++kt) {
            bf16x8 a0 = lds_afrag(smb, L_XF, 8, 0, kt, lane);
            bf16x8 a1 = lds_afrag(smb, L_XF, 8, 1, kt, lane);
            #pragma unroll
            for (int i = 0; i < 2; ++i) {
                bf16x8 b = *(const bf16x8*)(ws + ((size_t)(CH_WC + ((n0 + i) * 8 + kt) * 64) + lane) * 8);
                accW[i][0] = MFMA(a0, b, accW[i][0]);
                accW[i][1] = MFMA(a1, b, accW[i][1]);
            }
        }
        #pragma unroll
        for (int i = 0; i < 2; ++i) {
            int c = (n0 + i) * 16 + col;
            float bo_ = bo[c], bc_ = bc[c];
            float scl = gamma[c] * rsqrtf(var[c] + 1e-6f);
            float mu_ = mu[c], be_ = beta[c];
            #pragma unroll
            for (int mt = 0; mt < 2; ++mt)
                #pragma unroll
                for (int r = 0; r < 4; ++r) {
                    int vox = mt * 16 + qd * 4 + r;
                    float res = fmaxf(accW[i][mt][r] + bc_, 0.f);
                    float iv  = accF[i][mt][r] + bo_;
                    out[base + vox * 256 + c] = (res + iv - mu_) * scl + be_;
                }
        }
    }
}

extern "C" void kernel_launch(void* const* d_in, const int* in_sizes, int n_in,
                              void* d_out, int out_size, void* d_ws, size_t ws_size,
                              hipStream_t stream) {
    const float* x     = (const float*)d_in[0];
    const float* Wq    = (const float*)d_in[1];
    const float* bq    = (const float*)d_in[2];
    const float* Wk    = (const float*)d_in[3];
    const float* bk    = (const float*)d_in[4];
    const float* Wv    = (const float*)d_in[5];
    const float* bv    = (const float*)d_in[6];
    const float* W1    = (const float*)d_in[7];
    const float* b1    = (const float*)d_in[8];
    const float* Wo    = (const float*)d_in[9];
    const float* bo    = (const float*)d_in[10];
    const float* Wc    = (const float*)d_in[11];
    const float* bc    = (const float*)d_in[12];
    const float* gamma = (const float*)d_in[13];
    const float* beta  = (const float*)d_in[14];
    const float* mu    = (const float*)d_in[15];
    const float* var   = (const float*)d_in[16];
    float* out = (float*)d_out;
    bf16* ws = (bf16*)d_ws;

    pack_w<<<(CH_TOT + 255) / 256, 256, 0, stream>>>(Wq, Wk, Wv, W1, Wo, Wc, ws);

    const int n = in_sizes[0] / CIN;           // 131072 voxels
    const int blocks = n / TILE;               // 4096
    const size_t smem = LDS_ELEMS * sizeof(bf16);  // 117760 B
    hipFuncSetAttribute(reinterpret_cast<const void*>(msa_mfma),
                        hipFuncAttributeMaxDynamicSharedMemorySize, (int)smem);
    msa_mfma<<<blocks, THREADS, smem, stream>>>(x, ws, bq, bk, bv, b1, bo, bc,
                                                gamma, beta, mu, var, out);
}